// Round 7
// baseline (711.806 us; speedup 1.0000x reference)
//
#include <hip/hip_runtime.h>

// EmbedLoopyBP on gfx950 — round 7.
// R6 + (1) naW consumed as bf16 (fp32 atomic accum -> tiny convert kernel),
// halving the random 256B-row gather traffic through L2/L3; (2) Wc^T/We^T
// pre-converted to bf16 once (k_prep) — k_iter blocks do 4 tiles (256 slots)
// amortizing the single wts stage+barrier; (3) all wave-local barriers
// removed (xs/os/efs writer threads and reader lanes are the same wave);
// (4) one upfront memset, scan2 folded into scan3.

#define NN 50000
#define NE 800000
#define NG 128
#define D 64
#define LDE 36
#define LDW 66
#define LDO 72

typedef unsigned short u16;
typedef unsigned int u32;
typedef __bf16 bf16x8 __attribute__((ext_vector_type(8)));
typedef float f32x4 __attribute__((ext_vector_type(4)));

__device__ __forceinline__ float b2f(u16 u){ u32 x=((u32)u)<<16; float f; __builtin_memcpy(&f,&x,4); return f; }
__device__ __forceinline__ u16 f2b(float f){ u32 x; __builtin_memcpy(&x,&f,4); x += 0x7fffu + ((x>>16)&1u); return (u16)(x>>16); }
__device__ __forceinline__ u32 pack2(float a, float b){ return (u32)f2b(a) | ((u32)f2b(b)<<16); }
__device__ __forceinline__ void unpack8(uint4 v, float* o){
  o[0]=b2f((u16)(v.x&0xffffu)); o[1]=b2f((u16)(v.x>>16));
  o[2]=b2f((u16)(v.y&0xffffu)); o[3]=b2f((u16)(v.y>>16));
  o[4]=b2f((u16)(v.z&0xffffu)); o[5]=b2f((u16)(v.z>>16));
  o[6]=b2f((u16)(v.w&0xffffu)); o[7]=b2f((u16)(v.w>>16));
}

// ---------------- one-time weight transpose+convert ----------------
__global__ __launch_bounds__(256) void k_prep(const float* __restrict__ Wc, const float* __restrict__ We,
                                              u16* __restrict__ wcT, u16* __restrict__ weT){
  int i = blockIdx.x*256 + threadIdx.x;
  if (i < 4096){ int n=i>>6, k=i&63; wcT[i] = f2b(Wc[k*D+n]); }          // wcT[n][k]
  int j = i - 4096;
  if (j >= 0 && j < 2048){ int n=j>>5, k=j&31; weT[j] = f2b(We[k*D+n]); } // weT[n][k]
}

// ---------------- naW fp32 -> bf16 (+ optional re-zero of another buffer) ----------------
template<int ZERO>
__global__ __launch_bounds__(256) void k_cvt(const float* __restrict__ srcv, u16* __restrict__ dstb,
                                             float* __restrict__ zbuf){
  size_t i = (size_t)(blockIdx.x*256 + threadIdx.x)*4;
  float4 v = *(const float4*)(srcv + i);
  *(uint2*)(dstb + i) = make_uint2(pack2(v.x,v.y), pack2(v.z,v.w));
  if (ZERO) *(float4*)(zbuf + i) = make_float4(0.f,0.f,0.f,0.f);
}

// ---------------- node linear: inlb = bf16(node_feat @ Wn + bn) ----------------
__global__ __launch_bounds__(256) void k_inl(const float* __restrict__ nf, const float* __restrict__ Wn,
                                             const float* __restrict__ bn, u16* __restrict__ inlb){
  __shared__ float w[D*D];
  for (int i=threadIdx.x;i<D*D;i+=256) w[i]=Wn[i];
  __syncthreads();
  const int d = threadIdx.x&63;
  const int n = blockIdx.x*4 + (threadIdx.x>>6);
  if (n>=NN) return;
  float v = bn[d];
  const float* row = nf + (size_t)n*D;
  #pragma unroll 8
  for (int k=0;k<D;k++) v += row[k]*w[k*D+d];
  inlb[(size_t)n*D+d] = f2b(v);
}

// ---------------- imP[perm[e]] = edge_feat@We + be + inl[src[e]]  (bf16) ----------------
__global__ __launch_bounds__(256) void k_im(const float* __restrict__ ef, const u16* __restrict__ weT,
                                            const float* __restrict__ be, const u16* __restrict__ inlb,
                                            const int* __restrict__ src, const int* __restrict__ perm,
                                            u16* __restrict__ imP){
  __shared__ __align__(16) u16 efs[64*LDE];
  __shared__ __align__(16) u16 wts[64*LDE];
  __shared__ float os[64*68];
  const int t = threadIdx.x;
  const int ebase = blockIdx.x*64;
  { // stage We^T bf16 from pre-converted global
    int n=t&63, k0=(t>>6)*8;
    *(uint4*)&wts[n*LDE + k0] = *(const uint4*)(weT + n*32 + k0);
  }
  { // stage edge_feat bf16 (coalesced float4 reads); wave-local rows
    int e=t>>2, k0=(t&3)*8;
    const float* p = ef + (size_t)(ebase+e)*32 + k0;
    float4 v0=*(const float4*)p, v1=*(const float4*)(p+4);
    uint4 pk = make_uint4(pack2(v0.x,v0.y),pack2(v0.z,v0.w),pack2(v1.x,v1.y),pack2(v1.z,v1.w));
    *(uint4*)&efs[e*LDE + k0] = pk;
  }
  __syncthreads();   // for cross-wave wts only
  { // MFMA 16x16x32 (K=32, one step)
    int w=t>>6, lane=t&63, q=lane>>4, mr=lane&15;
    int rowb=w*16;
    bf16x8 A = *(const bf16x8*)&efs[(rowb+mr)*LDE + q*8];
    #pragma unroll
    for (int nt=0;nt<4;nt++){
      bf16x8 B = *(const bf16x8*)&wts[(nt*16+mr)*LDE + q*8];
      f32x4 acc = {0.f,0.f,0.f,0.f};
      acc = __builtin_amdgcn_mfma_f32_16x16x32_bf16(A,B,acc,0,0,0);
      #pragma unroll
      for (int r=0;r<4;r++) os[(rowb+q*4+r)*68 + nt*16+mr] = acc[r];
    }
  }
  // no barrier: os rows read below are wave-local
  { // epilogue: + be + inlb[src[e]] -> bf16, full-row scatter to imP[perm[e]]
    int e=t>>2, d0=(t&3)*16;
    const size_t eg = (size_t)(ebase+e);
    const int s = src[eg], ps = perm[eg];
    const u16* ip = inlb + (size_t)s*D + d0;
    uint4 iv0 = *(const uint4*)ip, iv1 = *(const uint4*)(ip+8);
    float il[16]; unpack8(iv0,il); unpack8(iv1,il+8);
    float x[16];
    #pragma unroll
    for (int j=0;j<16;j++) x[j] = os[e*68 + d0 + j] + be[d0+j] + il[j];
    uint4 p0 = make_uint4(pack2(x[0],x[1]),pack2(x[2],x[3]),pack2(x[4],x[5]),pack2(x[6],x[7]));
    uint4 p1 = make_uint4(pack2(x[8],x[9]),pack2(x[10],x[11]),pack2(x[12],x[13]),pack2(x[14],x[15]));
    u16* op = imP + (size_t)ps*D + d0;
    *(uint4*)op = p0; *(uint4*)(op+8) = p1;
  }
}

// ---------------- iteration kernel: 256 slots/block, 4 tiles, 1 barrier ----------------
// MODE 0: x=relu(imP[slot]);                               revOut[prevP[slot]]=(x@Wc); naW_out += per-node
// MODE 1: x=relu(naWb[srcP]-revIn[slot]+bc+imP[slot]);     same outputs
template<int MODE>
__global__ __launch_bounds__(256) void k_iter(const u16* __restrict__ imP, const u16* __restrict__ revIn,
      const u16* __restrict__ naWb, const u16* __restrict__ wcT, const float* __restrict__ bc,
      const int* __restrict__ srcP, const int* __restrict__ prevP, const int* __restrict__ nodeP,
      u16* __restrict__ revOut, float* __restrict__ naW_out){
  __shared__ __align__(16) u16 xs[64*LDW];
  __shared__ __align__(16) u16 wts[64*LDW];
  __shared__ __align__(16) u16 os[64*LDO];
  __shared__ int nid[64];
  const int t = threadIdx.x;
  const int lane = t&63, w = t>>6;
  { // stage Wc^T bf16 from pre-converted global (only cross-wave LDS use)
    const int k0 = w*16;
    *(uint4*)&wts[lane*LDW + k0]     = *(const uint4*)(wcT + lane*64 + k0);
    *(uint4*)&wts[lane*LDW + k0 + 8] = *(const uint4*)(wcT + lane*64 + k0 + 8);
  }
  const int e = t>>2, d0 = (t&3)*16;
  float bcr[16];
  if (MODE == 1){
    float4 b0=*(const float4*)(bc+d0),   b1=*(const float4*)(bc+d0+4);
    float4 b2=*(const float4*)(bc+d0+8), b3=*(const float4*)(bc+d0+12);
    bcr[0]=b0.x;bcr[1]=b0.y;bcr[2]=b0.z;bcr[3]=b0.w; bcr[4]=b1.x;bcr[5]=b1.y;bcr[6]=b1.z;bcr[7]=b1.w;
    bcr[8]=b2.x;bcr[9]=b2.y;bcr[10]=b2.z;bcr[11]=b2.w; bcr[12]=b3.x;bcr[13]=b3.y;bcr[14]=b3.z;bcr[15]=b3.w;
  }
  __syncthreads();
  const int q = lane>>4, mr = lane&15;
  const int rowb = w*16;
  #pragma unroll 1
  for (int tile=0; tile<4; ++tile){
    const size_t tbase = (size_t)blockIdx.x*256 + (size_t)tile*64;
    if (lane < 16) nid[rowb + lane] = nodeP[tbase + rowb + lane];   // wave-local
    { // phase 1: all-stream reads except naWb row gather; xs wave-local
      const size_t slot = tbase + e;
      const u16* ip = imP + slot*D + d0;
      uint4 r0 = *(const uint4*)ip, r1 = *(const uint4*)(ip+8);
      float x[16]; unpack8(r0,x); unpack8(r1,x+8);
      if (MODE == 1){
        const int sp = srcP[slot];
        const u16* cp = revIn + slot*D + d0;
        uint4 c0=*(const uint4*)cp, c1=*(const uint4*)(cp+8);
        const u16* np_ = naWb + (size_t)sp*D + d0;
        uint4 n0=*(const uint4*)np_, n1=*(const uint4*)(np_+8);
        float cv[16], nv[16];
        unpack8(c0,cv); unpack8(c1,cv+8);
        unpack8(n0,nv); unpack8(n1,nv+8);
        #pragma unroll
        for (int j=0;j<16;j++) x[j] += nv[j] - cv[j] + bcr[j];
      }
      #pragma unroll
      for (int j=0;j<16;j++) x[j] = x[j]>0.f ? x[j] : 0.f;
      uint4 p0 = make_uint4(pack2(x[0],x[1]),pack2(x[2],x[3]),pack2(x[4],x[5]),pack2(x[6],x[7]));
      uint4 p1 = make_uint4(pack2(x[8],x[9]),pack2(x[10],x[11]),pack2(x[12],x[13]),pack2(x[14],x[15]));
      u16* qd = &xs[e*LDW + d0];
      *(uint4*)qd = p0; *(uint4*)(qd+8) = p1;
    }
    { // phase 2: MFMA (xs wave-local -> no barrier); scatter store + fused flush
      bf16x8 A0 = *(const bf16x8*)&xs[(rowb+mr)*LDW + q*8];
      bf16x8 A1 = *(const bf16x8*)&xs[(rowb+mr)*LDW + 32 + q*8];
      #pragma unroll
      for (int nt=0;nt<4;nt++){
        bf16x8 B0 = *(const bf16x8*)&wts[(nt*16+mr)*LDW + q*8];
        bf16x8 B1 = *(const bf16x8*)&wts[(nt*16+mr)*LDW + 32 + q*8];
        f32x4 acc = {0.f,0.f,0.f,0.f};
        acc = __builtin_amdgcn_mfma_f32_16x16x32_bf16(A0,B0,acc,0,0,0);
        acc = __builtin_amdgcn_mfma_f32_16x16x32_bf16(A1,B1,acc,0,0,0);
        #pragma unroll
        for (int r=0;r<4;r++) os[(rowb+q*4+r)*LDO + nt*16 + mr] = f2b(acc[r]);
      }
      const int lr = lane>>2, cc = lane&3;
      const int tgt = prevP[tbase + rowb + lr];
      u16* gp = revOut + (size_t)tgt*D + cc*16;
      *(uint4*)gp     = *(const uint4*)&os[(rowb+lr)*LDO + cc*16];
      *(uint4*)(gp+8) = *(const uint4*)&os[(rowb+lr)*LDO + cc*16 + 8];
      // fused per-node reduction (wave-local os + nid)
      float acc = 0.f;
      int curn = nid[rowb];
      #pragma unroll 4
      for (int i=0;i<16;++i){
        int n = nid[rowb+i];                 // wave-uniform
        if (n != curn){
          atomicAdd(&naW_out[(size_t)curn*D + lane], acc);
          curn = n; acc = 0.f;
        }
        acc += b2f(os[(rowb+i)*LDO + lane]);
      }
      atomicAdd(&naW_out[(size_t)curn*D + lane], acc);
    }
  }
}

// ---------------- final BP step (barrier-free): e2n += per-node ----------------
__global__ __launch_bounds__(256) void k_last(const u16* __restrict__ imP, const u16* __restrict__ revIn,
      const u16* __restrict__ naWb, const float* __restrict__ bc,
      const int* __restrict__ srcP, const int* __restrict__ nodeP,
      float* __restrict__ e2n){
  __shared__ __align__(16) u16 xs[64*LDW];
  __shared__ int nid[64];
  const int t = threadIdx.x;
  const int lane = t&63, w = t>>6;
  const size_t sbase = (size_t)blockIdx.x*64;
  if (lane < 16) nid[w*16+lane] = nodeP[sbase + w*16 + lane];   // wave-local
  {
    const int e = t>>2, d0 = (t&3)*16;
    const size_t slot = sbase + e;
    const u16* ip = imP + slot*D + d0;
    uint4 r0 = *(const uint4*)ip, r1 = *(const uint4*)(ip+8);
    float x[16]; unpack8(r0,x); unpack8(r1,x+8);
    const int sp = srcP[slot];
    const u16* cp = revIn + slot*D + d0;
    uint4 c0 = *(const uint4*)cp, c1 = *(const uint4*)(cp+8);
    const u16* np_ = naWb + (size_t)sp*D + d0;
    uint4 n0 = *(const uint4*)np_, n1 = *(const uint4*)(np_+8);
    float cv[16], nv[16];
    unpack8(c0,cv); unpack8(c1,cv+8);
    unpack8(n0,nv); unpack8(n1,nv+8);
    #pragma unroll
    for (int j=0;j<16;j++){ x[j] += nv[j] - cv[j] + bc[d0+j]; x[j] = x[j]>0.f ? x[j] : 0.f; }
    uint4 p0 = make_uint4(pack2(x[0],x[1]),pack2(x[2],x[3]),pack2(x[4],x[5]),pack2(x[6],x[7]));
    uint4 p1 = make_uint4(pack2(x[8],x[9]),pack2(x[10],x[11]),pack2(x[12],x[13]),pack2(x[14],x[15]));
    u16* qd = &xs[e*LDW + d0];
    *(uint4*)qd = p0; *(uint4*)(qd+8) = p1;
  }
  { // wave-local reduction, no barrier
    float acc = 0.f;
    int curn = nid[w*16];
    #pragma unroll 4
    for (int i=0;i<16;++i){
      int n = nid[w*16+i];
      if (n != curn){
        atomicAdd(&e2n[(size_t)curn*D + lane], acc);
        curn = n; acc = 0.f;
      }
      acc += b2f(xs[(w*16+i)*LDW + lane]);
    }
    atomicAdd(&e2n[(size_t)curn*D + lane], acc);
  }
}

// ---------------- CSR build ----------------
__global__ void k_hist(const int* __restrict__ dst, int* __restrict__ cnt){
  int e = blockIdx.x*256 + threadIdx.x;
  atomicAdd(&cnt[dst[e]], 1);
}
__global__ __launch_bounds__(1024) void k_scan1(const int* __restrict__ cnt, int* __restrict__ outv,
                                                int* __restrict__ bsums, int n){
  __shared__ int sh[1024];
  int i = blockIdx.x*1024 + threadIdx.x;
  int v = (i<n)? cnt[i] : 0;
  sh[threadIdx.x]=v;
  __syncthreads();
  for (int off=1; off<1024; off<<=1){
    int tv = (threadIdx.x>=(unsigned)off)? sh[threadIdx.x-off] : 0;
    __syncthreads();
    sh[threadIdx.x] += tv;
    __syncthreads();
  }
  if (i<n) outv[i] = sh[threadIdx.x] - v;
  if (threadIdx.x==1023) bsums[blockIdx.x] = sh[1023];
}
__global__ __launch_bounds__(1024) void k_scan3(int* __restrict__ off, int* __restrict__ cur,
                                                const int* __restrict__ bsums, int n){
  __shared__ int spref;
  if (threadIdx.x < 64){
    int v = ((int)threadIdx.x < (int)blockIdx.x) ? bsums[threadIdx.x] : 0;
    #pragma unroll
    for (int o=1;o<64;o<<=1) v += __shfl_xor(v, o, 64);
    if (threadIdx.x==0) spref = v;
  }
  __syncthreads();
  int i = blockIdx.x*1024 + threadIdx.x;
  if (i<n){ int v = off[i] + spref; off[i]=v; cur[i]=v; }
}
__global__ void k_fill(const int* __restrict__ dst, const int* __restrict__ src,
                       int* __restrict__ cur, int* __restrict__ perm,
                       int* __restrict__ srcP, int* __restrict__ nodeP){
  int e = blockIdx.x*256 + threadIdx.x;
  int d = dst[e];
  int pos = atomicAdd(&cur[d], 1);
  perm[e] = pos;
  srcP[pos] = src[e];
  nodeP[pos] = d;
}
__global__ void k_prev(const int* __restrict__ rev, const int* __restrict__ perm, int* __restrict__ prevP){
  int e = blockIdx.x*256 + threadIdx.x;
  prevP[perm[e]] = perm[rev[e]];
}

// ---------------- final: relu(e2n)@Wo+bo -> relu -> graph segsum ----------------
__global__ __launch_bounds__(256) void k_final(const float* __restrict__ e2n, const float* __restrict__ Wo,
                                               const float* __restrict__ bo, const int* __restrict__ gid,
                                               float* __restrict__ yacc){
  __shared__ float w[D*D];
  for (int i=threadIdx.x;i<D*D;i+=256) w[i]=Wo[i];
  __syncthreads();
  const int d = threadIdx.x&63, sub = threadIdx.x>>6;
  const int n0 = blockIdx.x*32 + sub*8;
  const float bod = bo[d];
  float acc=0.f; int curg=-1;
  for (int i=0;i<8;i++){
    int n=n0+i;
    if (n>=NN) break;
    int g = gid[n];
    if (g!=curg){ if (curg>=0) atomicAdd(&yacc[curg*D+d], acc); curg=g; acc=0.f; }
    float v=bod;
    const float* er = e2n + (size_t)n*D;
    #pragma unroll 8
    for (int k=0;k<D;k++){ float h=er[k]; h = h>0.f?h:0.f; v += h*w[k*D+d]; }
    acc += (v>0.f ? v : 0.f);
  }
  if (curg>=0) atomicAdd(&yacc[curg*D+d], acc);
}
__global__ void k_out(const float* __restrict__ yacc, float* __restrict__ outp){
  int i = blockIdx.x*256 + threadIdx.x;
  if (i<NG*D){ float v=yacc[i]; outp[i]= v>0.f?v:0.f; }
}

// ---------------- workspace layout ----------------
static constexpr size_t SZ_E   = (size_t)NE*D*2;          // 102.4 MB bf16 edge array
static constexpr size_t SZ_NF4 = (size_t)NN*D*4;          // 12.8 MB fp32 node array
static constexpr size_t SZ_NB  = (size_t)NN*D*2;          // 6.4 MB bf16 node array
static constexpr size_t OFF_IMP  = 0;
static constexpr size_t OFF_RVA  = SZ_E;
static constexpr size_t OFF_RVB  = 2*SZ_E;
// contiguous zero region: csr_cur | naW0 | naW1 | e2n | yacc
static constexpr size_t OFF_CCUR = 3*SZ_E;
static constexpr size_t OFF_NA0  = OFF_CCUR + 200064;
static constexpr size_t OFF_NA1  = OFF_NA0 + SZ_NF4;
static constexpr size_t OFF_E2N  = OFF_NA1 + SZ_NF4;
static constexpr size_t OFF_YACC = OFF_E2N + SZ_NF4;
static constexpr size_t ZERO_SZ  = 200064 + 3*SZ_NF4 + (size_t)NG*D*4;
static constexpr size_t OFF_NAB  = OFF_YACC + (size_t)NG*D*4;   // bf16 naW (single reused buffer)
static constexpr size_t OFF_INL  = OFF_NAB + SZ_NB;
static constexpr size_t OFF_COFF = OFF_INL + SZ_NB;
static constexpr size_t OFF_PERM = OFF_COFF + 200064;
static constexpr size_t OFF_SRCP = OFF_PERM + (size_t)NE*4;
static constexpr size_t OFF_PRVP = OFF_SRCP + (size_t)NE*4;
static constexpr size_t OFF_NODP = OFF_PRVP + (size_t)NE*4;
static constexpr size_t OFF_BS   = OFF_NODP + (size_t)NE*4;
static constexpr size_t OFF_WCT  = OFF_BS + 256;
static constexpr size_t OFF_WET  = OFF_WCT + 8192;

extern "C" void kernel_launch(void* const* d_in, const int* in_sizes, int n_in,
                              void* d_out, int out_size, void* d_ws, size_t ws_size,
                              hipStream_t stream) {
  const float* node_feat = (const float*)d_in[0];
  const float* edge_feat = (const float*)d_in[1];
  const int*   src       = (const int*)d_in[2];
  const int*   dst       = (const int*)d_in[3];
  const int*   rev       = (const int*)d_in[4];
  const int*   gid       = (const int*)d_in[5];
  const float* Wn = (const float*)d_in[7];
  const float* bn = (const float*)d_in[8];
  const float* We = (const float*)d_in[9];
  const float* be = (const float*)d_in[10];
  const float* Wc = (const float*)d_in[11];
  const float* bc = (const float*)d_in[12];
  const float* Wo = (const float*)d_in[13];
  const float* bo = (const float*)d_in[14];

  char* ws = (char*)d_ws;
  u16*   imP     = (u16*)(ws + OFF_IMP);
  u16*   revA    = (u16*)(ws + OFF_RVA);
  u16*   revB    = (u16*)(ws + OFF_RVB);
  float* naW0    = (float*)(ws + OFF_NA0);
  float* naW1    = (float*)(ws + OFF_NA1);
  float* e2n     = (float*)(ws + OFF_E2N);
  float* yacc    = (float*)(ws + OFF_YACC);
  u16*   naWb    = (u16*)(ws + OFF_NAB);
  u16*   inlb    = (u16*)(ws + OFF_INL);
  int*   csr_off = (int*)(ws + OFF_COFF);
  int*   csr_cur = (int*)(ws + OFF_CCUR);
  int*   perm    = (int*)(ws + OFF_PERM);
  int*   srcP    = (int*)(ws + OFF_SRCP);
  int*   prevP   = (int*)(ws + OFF_PRVP);
  int*   nodeP   = (int*)(ws + OFF_NODP);
  int*   bsums   = (int*)(ws + OFF_BS);
  u16*   wcT     = (u16*)(ws + OFF_WCT);
  u16*   weT     = (u16*)(ws + OFF_WET);

  // one upfront memset: csr_cur + naW0 + naW1 + e2n + yacc
  hipMemsetAsync(ws + OFF_CCUR, 0, ZERO_SZ, stream);

  // CSR build
  k_hist <<<NE/256, 256, 0, stream>>>(dst, csr_cur);
  k_scan1<<<49, 1024, 0, stream>>>(csr_cur, csr_off, bsums, NN);
  k_scan3<<<49, 1024, 0, stream>>>(csr_off, csr_cur, bsums, NN);
  k_fill <<<NE/256, 256, 0, stream>>>(dst, src, csr_cur, perm, srcP, nodeP);
  k_prev <<<NE/256, 256, 0, stream>>>(rev, perm, prevP);

  // weights prep + front end
  k_prep<<<24, 256, 0, stream>>>(Wc, We, wcT, weT);
  k_inl <<<NN/4, 256, 0, stream>>>(node_feat, Wn, bn, inlb);
  k_im  <<<NE/64, 256, 0, stream>>>(edge_feat, weT, be, inlb, src, perm, imP);

  // loopy BP
  k_iter<0><<<NE/256, 256, 0, stream>>>(imP, revA, naWb, wcT, bc, srcP, prevP, nodeP, revA, naW0);
  k_cvt<0><<<3125, 256, 0, stream>>>(naW0, naWb, (float*)nullptr);
  k_iter<1><<<NE/256, 256, 0, stream>>>(imP, revA, naWb, wcT, bc, srcP, prevP, nodeP, revB, naW1);
  k_cvt<1><<<3125, 256, 0, stream>>>(naW1, naWb, naW0);     // convert + re-zero naW0
  k_iter<1><<<NE/256, 256, 0, stream>>>(imP, revB, naWb, wcT, bc, srcP, prevP, nodeP, revA, naW0);
  k_cvt<0><<<3125, 256, 0, stream>>>(naW0, naWb, (float*)nullptr);
  k_last<<<NE/64, 256, 0, stream>>>(imP, revA, naWb, bc, srcP, nodeP, e2n);

  // head
  k_final<<<(NN+31)/32, 256, 0, stream>>>(e2n, Wo, bo, gid, yacc);
  k_out<<<(NG*D)/256, 256, 0, stream>>>(yacc, (float*)d_out);
}

// Round 8
// 684.311 us; speedup vs baseline: 1.0402x; 1.0402x over previous
//
#include <hip/hip_runtime.h>

// EmbedLoopyBP on gfx950 — round 8.
// R6's 64-slot/12500-block k_iter scheduling (high occupancy, short blocks)
// + R7's traffic wins (bf16 naWb consumption, pre-converted wcT/weT).
// Single barrier per k_iter block (wts staging only; xs/os/nid are wave-local:
// phase-1 writers of rows 16w..16w+15 are exactly wave w's threads).

#define NN 50000
#define NE 800000
#define NG 128
#define D 64
#define LDE 36
#define LDW 66
#define LDO 72

typedef unsigned short u16;
typedef unsigned int u32;
typedef __bf16 bf16x8 __attribute__((ext_vector_type(8)));
typedef float f32x4 __attribute__((ext_vector_type(4)));

__device__ __forceinline__ float b2f(u16 u){ u32 x=((u32)u)<<16; float f; __builtin_memcpy(&f,&x,4); return f; }
__device__ __forceinline__ u16 f2b(float f){ u32 x; __builtin_memcpy(&x,&f,4); x += 0x7fffu + ((x>>16)&1u); return (u16)(x>>16); }
__device__ __forceinline__ u32 pack2(float a, float b){ return (u32)f2b(a) | ((u32)f2b(b)<<16); }
__device__ __forceinline__ void unpack8(uint4 v, float* o){
  o[0]=b2f((u16)(v.x&0xffffu)); o[1]=b2f((u16)(v.x>>16));
  o[2]=b2f((u16)(v.y&0xffffu)); o[3]=b2f((u16)(v.y>>16));
  o[4]=b2f((u16)(v.z&0xffffu)); o[5]=b2f((u16)(v.z>>16));
  o[6]=b2f((u16)(v.w&0xffffu)); o[7]=b2f((u16)(v.w>>16));
}

// ---------------- one-time weight transpose+convert ----------------
__global__ __launch_bounds__(256) void k_prep(const float* __restrict__ Wc, const float* __restrict__ We,
                                              u16* __restrict__ wcT, u16* __restrict__ weT){
  int i = blockIdx.x*256 + threadIdx.x;
  if (i < 4096){ int n=i>>6, k=i&63; wcT[i] = f2b(Wc[k*D+n]); }          // wcT[n][k]
  int j = i - 4096;
  if (j >= 0 && j < 2048){ int n=j>>5, k=j&31; weT[j] = f2b(We[k*D+n]); } // weT[n][k]
}

// ---------------- naW fp32 -> bf16 (+ optional re-zero of another buffer) ----------------
template<int ZERO>
__global__ __launch_bounds__(256) void k_cvt(const float* __restrict__ srcv, u16* __restrict__ dstb,
                                             float* __restrict__ zbuf){
  size_t i = (size_t)(blockIdx.x*256 + threadIdx.x)*4;
  float4 v = *(const float4*)(srcv + i);
  *(uint2*)(dstb + i) = make_uint2(pack2(v.x,v.y), pack2(v.z,v.w));
  if (ZERO) *(float4*)(zbuf + i) = make_float4(0.f,0.f,0.f,0.f);
}

// ---------------- node linear: inlb = bf16(node_feat @ Wn + bn) ----------------
__global__ __launch_bounds__(256) void k_inl(const float* __restrict__ nf, const float* __restrict__ Wn,
                                             const float* __restrict__ bn, u16* __restrict__ inlb){
  __shared__ float w[D*D];
  for (int i=threadIdx.x;i<D*D;i+=256) w[i]=Wn[i];
  __syncthreads();
  const int d = threadIdx.x&63;
  const int n = blockIdx.x*4 + (threadIdx.x>>6);
  if (n>=NN) return;
  float v = bn[d];
  const float* row = nf + (size_t)n*D;
  #pragma unroll 8
  for (int k=0;k<D;k++) v += row[k]*w[k*D+d];
  inlb[(size_t)n*D+d] = f2b(v);
}

// ---------------- imP[perm[e]] = edge_feat@We + be + inl[src[e]]  (bf16) ----------------
__global__ __launch_bounds__(256) void k_im(const float* __restrict__ ef, const u16* __restrict__ weT,
                                            const float* __restrict__ be, const u16* __restrict__ inlb,
                                            const int* __restrict__ src, const int* __restrict__ perm,
                                            u16* __restrict__ imP){
  __shared__ __align__(16) u16 efs[64*LDE];
  __shared__ __align__(16) u16 wts[64*LDE];
  __shared__ float os[64*68];
  const int t = threadIdx.x;
  const int ebase = blockIdx.x*64;
  { // stage We^T bf16 from pre-converted global
    int n=t&63, k0=(t>>6)*8;
    *(uint4*)&wts[n*LDE + k0] = *(const uint4*)(weT + n*32 + k0);
  }
  { // stage edge_feat bf16 (coalesced float4 reads); wave-local rows
    int e=t>>2, k0=(t&3)*8;
    const float* p = ef + (size_t)(ebase+e)*32 + k0;
    float4 v0=*(const float4*)p, v1=*(const float4*)(p+4);
    uint4 pk = make_uint4(pack2(v0.x,v0.y),pack2(v0.z,v0.w),pack2(v1.x,v1.y),pack2(v1.z,v1.w));
    *(uint4*)&efs[e*LDE + k0] = pk;
  }
  __syncthreads();   // for cross-wave wts only
  { // MFMA 16x16x32 (K=32, one step)
    int w=t>>6, lane=t&63, q=lane>>4, mr=lane&15;
    int rowb=w*16;
    bf16x8 A = *(const bf16x8*)&efs[(rowb+mr)*LDE + q*8];
    #pragma unroll
    for (int nt=0;nt<4;nt++){
      bf16x8 B = *(const bf16x8*)&wts[(nt*16+mr)*LDE + q*8];
      f32x4 acc = {0.f,0.f,0.f,0.f};
      acc = __builtin_amdgcn_mfma_f32_16x16x32_bf16(A,B,acc,0,0,0);
      #pragma unroll
      for (int r=0;r<4;r++) os[(rowb+q*4+r)*68 + nt*16+mr] = acc[r];
    }
  }
  // no barrier: os rows read below are wave-local
  { // epilogue: + be + inlb[src[e]] -> bf16, full-row scatter to imP[perm[e]]
    int e=t>>2, d0=(t&3)*16;
    const size_t eg = (size_t)(ebase+e);
    const int s = src[eg], ps = perm[eg];
    const u16* ip = inlb + (size_t)s*D + d0;
    uint4 iv0 = *(const uint4*)ip, iv1 = *(const uint4*)(ip+8);
    float il[16]; unpack8(iv0,il); unpack8(iv1,il+8);
    float x[16];
    #pragma unroll
    for (int j=0;j<16;j++) x[j] = os[e*68 + d0 + j] + be[d0+j] + il[j];
    uint4 p0 = make_uint4(pack2(x[0],x[1]),pack2(x[2],x[3]),pack2(x[4],x[5]),pack2(x[6],x[7]));
    uint4 p1 = make_uint4(pack2(x[8],x[9]),pack2(x[10],x[11]),pack2(x[12],x[13]),pack2(x[14],x[15]));
    u16* op = imP + (size_t)ps*D + d0;
    *(uint4*)op = p0; *(uint4*)(op+8) = p1;
  }
}

// ---------------- iteration kernel: 64 slots/block, 1 barrier ----------------
// MODE 0: x=relu(imP[slot]);                               revOut[prevP[slot]]=(x@Wc); naW_out += per-node
// MODE 1: x=relu(naWb[srcP]-revIn[slot]+bc+imP[slot]);     same outputs
template<int MODE>
__global__ __launch_bounds__(256) void k_iter(const u16* __restrict__ imP, const u16* __restrict__ revIn,
      const u16* __restrict__ naWb, const u16* __restrict__ wcT, const float* __restrict__ bc,
      const int* __restrict__ srcP, const int* __restrict__ prevP, const int* __restrict__ nodeP,
      u16* __restrict__ revOut, float* __restrict__ naW_out){
  __shared__ __align__(16) u16 xs[64*LDW];
  __shared__ __align__(16) u16 wts[64*LDW];
  __shared__ __align__(16) u16 os[64*LDO];
  __shared__ int nid[64];
  const int t = threadIdx.x;
  const int lane = t&63, w = t>>6;
  const size_t sbase = (size_t)blockIdx.x*64;
  { // stage Wc^T bf16 from pre-converted global (only cross-wave LDS use)
    const int k0 = w*16;
    *(uint4*)&wts[lane*LDW + k0]     = *(const uint4*)(wcT + lane*64 + k0);
    *(uint4*)&wts[lane*LDW + k0 + 8] = *(const uint4*)(wcT + lane*64 + k0 + 8);
  }
  if (lane < 16) nid[w*16 + lane] = nodeP[sbase + w*16 + lane];   // wave-local
  __syncthreads();
  { // phase 1: all-stream reads except naWb row gather; xs rows wave-local
    const int e = t>>2, d0 = (t&3)*16;
    const size_t slot = sbase + e;
    const u16* ip = imP + slot*D + d0;
    uint4 r0 = *(const uint4*)ip, r1 = *(const uint4*)(ip+8);
    float x[16]; unpack8(r0,x); unpack8(r1,x+8);
    if (MODE == 1){
      const int sp = srcP[slot];
      const u16* cp = revIn + slot*D + d0;
      uint4 c0=*(const uint4*)cp, c1=*(const uint4*)(cp+8);
      const u16* np_ = naWb + (size_t)sp*D + d0;
      uint4 n0=*(const uint4*)np_, n1=*(const uint4*)(np_+8);
      float cv[16], nv[16];
      unpack8(c0,cv); unpack8(c1,cv+8);
      unpack8(n0,nv); unpack8(n1,nv+8);
      #pragma unroll
      for (int j=0;j<16;j++) x[j] += nv[j] - cv[j] + bc[d0+j];
    }
    #pragma unroll
    for (int j=0;j<16;j++) x[j] = x[j]>0.f ? x[j] : 0.f;
    uint4 p0 = make_uint4(pack2(x[0],x[1]),pack2(x[2],x[3]),pack2(x[4],x[5]),pack2(x[6],x[7]));
    uint4 p1 = make_uint4(pack2(x[8],x[9]),pack2(x[10],x[11]),pack2(x[12],x[13]),pack2(x[14],x[15]));
    u16* qd = &xs[e*LDW + d0];
    *(uint4*)qd = p0; *(uint4*)(qd+8) = p1;
  }
  { // phase 2: MFMA (xs wave-local, no barrier); scatter store + fused flush
    const int q = lane>>4, mr = lane&15;
    const int rowb = w*16;
    bf16x8 A0 = *(const bf16x8*)&xs[(rowb+mr)*LDW + q*8];
    bf16x8 A1 = *(const bf16x8*)&xs[(rowb+mr)*LDW + 32 + q*8];
    #pragma unroll
    for (int nt=0;nt<4;nt++){
      bf16x8 B0 = *(const bf16x8*)&wts[(nt*16+mr)*LDW + q*8];
      bf16x8 B1 = *(const bf16x8*)&wts[(nt*16+mr)*LDW + 32 + q*8];
      f32x4 acc = {0.f,0.f,0.f,0.f};
      acc = __builtin_amdgcn_mfma_f32_16x16x32_bf16(A0,B0,acc,0,0,0);
      acc = __builtin_amdgcn_mfma_f32_16x16x32_bf16(A1,B1,acc,0,0,0);
      #pragma unroll
      for (int r=0;r<4;r++) os[(rowb+q*4+r)*LDO + nt*16 + mr] = f2b(acc[r]);
    }
    const int lr = lane>>2, cc = lane&3;
    const int tgt = prevP[sbase + rowb + lr];
    u16* gp = revOut + (size_t)tgt*D + cc*16;
    *(uint4*)gp     = *(const uint4*)&os[(rowb+lr)*LDO + cc*16];
    *(uint4*)(gp+8) = *(const uint4*)&os[(rowb+lr)*LDO + cc*16 + 8];
    // fused per-node reduction (wave-local os + nid)
    float acc = 0.f;
    int curn = nid[rowb];
    #pragma unroll 4
    for (int i=0;i<16;++i){
      int n = nid[rowb+i];                 // wave-uniform
      if (n != curn){
        atomicAdd(&naW_out[(size_t)curn*D + lane], acc);
        curn = n; acc = 0.f;
      }
      acc += b2f(os[(rowb+i)*LDO + lane]);
    }
    atomicAdd(&naW_out[(size_t)curn*D + lane], acc);
  }
}

// ---------------- final BP step (barrier-free): e2n += per-node ----------------
__global__ __launch_bounds__(256) void k_last(const u16* __restrict__ imP, const u16* __restrict__ revIn,
      const u16* __restrict__ naWb, const float* __restrict__ bc,
      const int* __restrict__ srcP, const int* __restrict__ nodeP,
      float* __restrict__ e2n){
  __shared__ __align__(16) u16 xs[64*LDW];
  __shared__ int nid[64];
  const int t = threadIdx.x;
  const int lane = t&63, w = t>>6;
  const size_t sbase = (size_t)blockIdx.x*64;
  if (lane < 16) nid[w*16+lane] = nodeP[sbase + w*16 + lane];   // wave-local
  {
    const int e = t>>2, d0 = (t&3)*16;
    const size_t slot = sbase + e;
    const u16* ip = imP + slot*D + d0;
    uint4 r0 = *(const uint4*)ip, r1 = *(const uint4*)(ip+8);
    float x[16]; unpack8(r0,x); unpack8(r1,x+8);
    const int sp = srcP[slot];
    const u16* cp = revIn + slot*D + d0;
    uint4 c0 = *(const uint4*)cp, c1 = *(const uint4*)(cp+8);
    const u16* np_ = naWb + (size_t)sp*D + d0;
    uint4 n0 = *(const uint4*)np_, n1 = *(const uint4*)(np_+8);
    float cv[16], nv[16];
    unpack8(c0,cv); unpack8(c1,cv+8);
    unpack8(n0,nv); unpack8(n1,nv+8);
    #pragma unroll
    for (int j=0;j<16;j++){ x[j] += nv[j] - cv[j] + bc[d0+j]; x[j] = x[j]>0.f ? x[j] : 0.f; }
    uint4 p0 = make_uint4(pack2(x[0],x[1]),pack2(x[2],x[3]),pack2(x[4],x[5]),pack2(x[6],x[7]));
    uint4 p1 = make_uint4(pack2(x[8],x[9]),pack2(x[10],x[11]),pack2(x[12],x[13]),pack2(x[14],x[15]));
    u16* qd = &xs[e*LDW + d0];
    *(uint4*)qd = p0; *(uint4*)(qd+8) = p1;
  }
  { // wave-local reduction, no barrier
    float acc = 0.f;
    int curn = nid[w*16];
    #pragma unroll 4
    for (int i=0;i<16;++i){
      int n = nid[w*16+i];
      if (n != curn){
        atomicAdd(&e2n[(size_t)curn*D + lane], acc);
        curn = n; acc = 0.f;
      }
      acc += b2f(xs[(w*16+i)*LDW + lane]);
    }
    atomicAdd(&e2n[(size_t)curn*D + lane], acc);
  }
}

// ---------------- CSR build ----------------
__global__ void k_hist(const int* __restrict__ dst, int* __restrict__ cnt){
  int e = blockIdx.x*256 + threadIdx.x;
  atomicAdd(&cnt[dst[e]], 1);
}
__global__ __launch_bounds__(1024) void k_scan1(const int* __restrict__ cnt, int* __restrict__ outv,
                                                int* __restrict__ bsums, int n){
  __shared__ int sh[1024];
  int i = blockIdx.x*1024 + threadIdx.x;
  int v = (i<n)? cnt[i] : 0;
  sh[threadIdx.x]=v;
  __syncthreads();
  for (int off=1; off<1024; off<<=1){
    int tv = (threadIdx.x>=(unsigned)off)? sh[threadIdx.x-off] : 0;
    __syncthreads();
    sh[threadIdx.x] += tv;
    __syncthreads();
  }
  if (i<n) outv[i] = sh[threadIdx.x] - v;
  if (threadIdx.x==1023) bsums[blockIdx.x] = sh[1023];
}
__global__ __launch_bounds__(1024) void k_scan3(int* __restrict__ off, int* __restrict__ cur,
                                                const int* __restrict__ bsums, int n){
  __shared__ int spref;
  if (threadIdx.x < 64){
    int v = ((int)threadIdx.x < (int)blockIdx.x) ? bsums[threadIdx.x] : 0;
    #pragma unroll
    for (int o=1;o<64;o<<=1) v += __shfl_xor(v, o, 64);
    if (threadIdx.x==0) spref = v;
  }
  __syncthreads();
  int i = blockIdx.x*1024 + threadIdx.x;
  if (i<n){ int v = off[i] + spref; off[i]=v; cur[i]=v; }
}
__global__ void k_fill(const int* __restrict__ dst, const int* __restrict__ src,
                       int* __restrict__ cur, int* __restrict__ perm,
                       int* __restrict__ srcP, int* __restrict__ nodeP){
  int e = blockIdx.x*256 + threadIdx.x;
  int d = dst[e];
  int pos = atomicAdd(&cur[d], 1);
  perm[e] = pos;
  srcP[pos] = src[e];
  nodeP[pos] = d;
}
__global__ void k_prev(const int* __restrict__ rev, const int* __restrict__ perm, int* __restrict__ prevP){
  int e = blockIdx.x*256 + threadIdx.x;
  prevP[perm[e]] = perm[rev[e]];
}

// ---------------- final: relu(e2n)@Wo+bo -> relu -> graph segsum ----------------
__global__ __launch_bounds__(256) void k_final(const float* __restrict__ e2n, const float* __restrict__ Wo,
                                               const float* __restrict__ bo, const int* __restrict__ gid,
                                               float* __restrict__ yacc){
  __shared__ float w[D*D];
  for (int i=threadIdx.x;i<D*D;i+=256) w[i]=Wo[i];
  __syncthreads();
  const int d = threadIdx.x&63, sub = threadIdx.x>>6;
  const int n0 = blockIdx.x*32 + sub*8;
  const float bod = bo[d];
  float acc=0.f; int curg=-1;
  for (int i=0;i<8;i++){
    int n=n0+i;
    if (n>=NN) break;
    int g = gid[n];
    if (g!=curg){ if (curg>=0) atomicAdd(&yacc[curg*D+d], acc); curg=g; acc=0.f; }
    float v=bod;
    const float* er = e2n + (size_t)n*D;
    #pragma unroll 8
    for (int k=0;k<D;k++){ float h=er[k]; h = h>0.f?h:0.f; v += h*w[k*D+d]; }
    acc += (v>0.f ? v : 0.f);
  }
  if (curg>=0) atomicAdd(&yacc[curg*D+d], acc);
}
__global__ void k_out(const float* __restrict__ yacc, float* __restrict__ outp){
  int i = blockIdx.x*256 + threadIdx.x;
  if (i<NG*D){ float v=yacc[i]; outp[i]= v>0.f?v:0.f; }
}

// ---------------- workspace layout ----------------
static constexpr size_t SZ_E   = (size_t)NE*D*2;          // 102.4 MB bf16 edge array
static constexpr size_t SZ_NF4 = (size_t)NN*D*4;          // 12.8 MB fp32 node array
static constexpr size_t SZ_NB  = (size_t)NN*D*2;          // 6.4 MB bf16 node array
static constexpr size_t OFF_IMP  = 0;
static constexpr size_t OFF_RVA  = SZ_E;
static constexpr size_t OFF_RVB  = 2*SZ_E;
// contiguous zero region: csr_cur | naW0 | naW1 | e2n | yacc
static constexpr size_t OFF_CCUR = 3*SZ_E;
static constexpr size_t OFF_NA0  = OFF_CCUR + 200064;
static constexpr size_t OFF_NA1  = OFF_NA0 + SZ_NF4;
static constexpr size_t OFF_E2N  = OFF_NA1 + SZ_NF4;
static constexpr size_t OFF_YACC = OFF_E2N + SZ_NF4;
static constexpr size_t ZERO_SZ  = 200064 + 3*SZ_NF4 + (size_t)NG*D*4;
static constexpr size_t OFF_NAB  = OFF_YACC + (size_t)NG*D*4;   // bf16 naW (single reused buffer)
static constexpr size_t OFF_INL  = OFF_NAB + SZ_NB;
static constexpr size_t OFF_COFF = OFF_INL + SZ_NB;
static constexpr size_t OFF_PERM = OFF_COFF + 200064;
static constexpr size_t OFF_SRCP = OFF_PERM + (size_t)NE*4;
static constexpr size_t OFF_PRVP = OFF_SRCP + (size_t)NE*4;
static constexpr size_t OFF_NODP = OFF_PRVP + (size_t)NE*4;
static constexpr size_t OFF_BS   = OFF_NODP + (size_t)NE*4;
static constexpr size_t OFF_WCT  = OFF_BS + 256;
static constexpr size_t OFF_WET  = OFF_WCT + 8192;

extern "C" void kernel_launch(void* const* d_in, const int* in_sizes, int n_in,
                              void* d_out, int out_size, void* d_ws, size_t ws_size,
                              hipStream_t stream) {
  const float* node_feat = (const float*)d_in[0];
  const float* edge_feat = (const float*)d_in[1];
  const int*   src       = (const int*)d_in[2];
  const int*   dst       = (const int*)d_in[3];
  const int*   rev       = (const int*)d_in[4];
  const int*   gid       = (const int*)d_in[5];
  const float* Wn = (const float*)d_in[7];
  const float* bn = (const float*)d_in[8];
  const float* We = (const float*)d_in[9];
  const float* be = (const float*)d_in[10];
  const float* Wc = (const float*)d_in[11];
  const float* bc = (const float*)d_in[12];
  const float* Wo = (const float*)d_in[13];
  const float* bo = (const float*)d_in[14];

  char* ws = (char*)d_ws;
  u16*   imP     = (u16*)(ws + OFF_IMP);
  u16*   revA    = (u16*)(ws + OFF_RVA);
  u16*   revB    = (u16*)(ws + OFF_RVB);
  float* naW0    = (float*)(ws + OFF_NA0);
  float* naW1    = (float*)(ws + OFF_NA1);
  float* e2n     = (float*)(ws + OFF_E2N);
  float* yacc    = (float*)(ws + OFF_YACC);
  u16*   naWb    = (u16*)(ws + OFF_NAB);
  u16*   inlb    = (u16*)(ws + OFF_INL);
  int*   csr_off = (int*)(ws + OFF_COFF);
  int*   csr_cur = (int*)(ws + OFF_CCUR);
  int*   perm    = (int*)(ws + OFF_PERM);
  int*   srcP    = (int*)(ws + OFF_SRCP);
  int*   prevP   = (int*)(ws + OFF_PRVP);
  int*   nodeP   = (int*)(ws + OFF_NODP);
  int*   bsums   = (int*)(ws + OFF_BS);
  u16*   wcT     = (u16*)(ws + OFF_WCT);
  u16*   weT     = (u16*)(ws + OFF_WET);

  // one upfront memset: csr_cur + naW0 + naW1 + e2n + yacc
  hipMemsetAsync(ws + OFF_CCUR, 0, ZERO_SZ, stream);

  // CSR build
  k_hist <<<NE/256, 256, 0, stream>>>(dst, csr_cur);
  k_scan1<<<49, 1024, 0, stream>>>(csr_cur, csr_off, bsums, NN);
  k_scan3<<<49, 1024, 0, stream>>>(csr_off, csr_cur, bsums, NN);
  k_fill <<<NE/256, 256, 0, stream>>>(dst, src, csr_cur, perm, srcP, nodeP);
  k_prev <<<NE/256, 256, 0, stream>>>(rev, perm, prevP);

  // weights prep + front end
  k_prep<<<24, 256, 0, stream>>>(Wc, We, wcT, weT);
  k_inl <<<NN/4, 256, 0, stream>>>(node_feat, Wn, bn, inlb);
  k_im  <<<NE/64, 256, 0, stream>>>(edge_feat, weT, be, inlb, src, perm, imP);

  // loopy BP
  k_iter<0><<<NE/64, 256, 0, stream>>>(imP, revA, naWb, wcT, bc, srcP, prevP, nodeP, revA, naW0);
  k_cvt<0><<<3125, 256, 0, stream>>>(naW0, naWb, (float*)nullptr);
  k_iter<1><<<NE/64, 256, 0, stream>>>(imP, revA, naWb, wcT, bc, srcP, prevP, nodeP, revB, naW1);
  k_cvt<1><<<3125, 256, 0, stream>>>(naW1, naWb, naW0);     // convert + re-zero naW0
  k_iter<1><<<NE/64, 256, 0, stream>>>(imP, revB, naWb, wcT, bc, srcP, prevP, nodeP, revA, naW0);
  k_cvt<0><<<3125, 256, 0, stream>>>(naW0, naWb, (float*)nullptr);
  k_last<<<NE/64, 256, 0, stream>>>(imP, revA, naWb, bc, srcP, nodeP, e2n);

  // head
  k_final<<<(NN+31)/32, 256, 0, stream>>>(e2n, Wo, bo, gid, yacc);
  k_out<<<(NG*D)/256, 256, 0, stream>>>(yacc, (float*)d_out);
}